// Round 5
// baseline (6477.071 us; speedup 1.0000x reference)
//
#include <hip/hip_runtime.h>

#define BB 64
#define TT 4096
#define IN0 32
#define HH 128
#define G3 384
#define NOUT 32

typedef _Float16 h2 __attribute__((ext_vector_type(2)));
typedef _Float16 h8 __attribute__((ext_vector_type(8)));
union H8 { h8 v; h2 p[4]; };

// One WG per batch element; wave-specialized single-barrier-per-step pipeline.
// Waves 0-7 (L1): layer-1 recurrence (8-way K-split, permlane reduce) + gi0 + x staging + out flush.
// Waves 8-11 (L0): layer-0 recurrence (4-way K-split) + fused fc on f16 h1.
// ALL register-array indices are compile-time constants (rule #20).
struct SM {
    alignas(16) _Float16 hf0[2][HH];      // h0 f16, parity by step
    alignas(16) _Float16 hf1[2][HH];      // h1 f16 (also feeds fc)
    alignas(16) float    gi0[2][HH][4];   // packed {r,z,n,pad} = W_ih0·x[t]+b_ih0
    alignas(16) _Float16 xh[2][16][IN0];  // x staged f16, 16-step chunks
    alignas(16) float    pfc[2][NOUT * 9];// fc partials (8-way K-split)
    alignas(16) float    outbuf[32][NOUT];// out ring, flushed every 16 steps
};

__device__ __forceinline__ float fast_sigmoid(float x) {
    x = fminf(fmaxf(x, -30.f), 30.f);
    float e = __expf(-x);
    return __builtin_amdgcn_rcpf(1.f + e);
}
__device__ __forceinline__ float fast_tanh(float x) {
    x = fminf(fmaxf(x, -15.f), 15.f);
    float e = __expf(-2.f * x);
    return (1.f - e) * __builtin_amdgcn_rcpf(1.f + e);
}
__device__ __forceinline__ float fdot2(h2 a, h2 b, float c) {
#if __has_builtin(__builtin_amdgcn_fdot2)
    return __builtin_amdgcn_fdot2(a, b, c, false);   // v_dot2_f32_f16, fp32 accum
#else
    return fmaf((float)a.x, (float)b.x, fmaf((float)a.y, (float)b.y, c));
#endif
}
__device__ __forceinline__ h2 cvt2(float a, float b) {
    h2 r; r.x = (_Float16)a; r.y = (_Float16)b; return r;
}
// quad-lane butterfly via DPP (VALU pipe, no LDS)
__device__ __forceinline__ float qxor1(float v) {   // lanes 0123 -> 1032
    return __int_as_float(__builtin_amdgcn_mov_dpp(__float_as_int(v), 0xB1, 0xF, 0xF, true));
}
__device__ __forceinline__ float qxor2(float v) {   // lanes 0123 -> 2301
    return __int_as_float(__builtin_amdgcn_mov_dpp(__float_as_int(v), 0x4E, 0xF, 0xF, true));
}
// lane l + lane l^32 via v_permlane32_swap (VALU; with a=b=v any half-swap
// semantics yields a'+b' = v[l] + v[l^32])
__device__ __forceinline__ float xor32sum(float v) {
    float a = v, b = v;
    asm volatile("v_permlane32_swap_b32 %0, %1" : "+v"(a), "+v"(b));
    return a + b;
}

// ---------------- waves 0-7: layer 1 + gi0 precompute + x staging + out flush --------
__device__ __forceinline__ void role_L1(
    SM& sm, const float* __restrict__ xb,
    const float* __restrict__ W_ih1, const float* __restrict__ W_hh1,
    const float* __restrict__ b_ih1, const float* __restrict__ b_hh1,
    const float* __restrict__ W_ih0, const float* __restrict__ b_ih0,
    float* __restrict__ outb, float* __restrict__ hstack_l1)
{
    const int tid = threadIdx.x;                   // 0..511
    const int l6 = tid & 63;
    const int kq8 = (l6 & 3) | ((l6 >> 3) & 4);    // K-slice id from lane bits {0,1,5}
    const int jslot = ((l6 >> 2) & 7) + (tid >> 6) * 8;   // 0..63
    const int jA0 = jslot, jA1 = jslot + 64;
    const bool lead8 = ((l6 & 35) == 0);           // bits 0,1,5 all zero
    const int jx = tid >> 2, kx = tid & 3;         // gi0 mapping (quad reduce)

    // weights: w[jj][term][m]; terms 0:wi_r 1:wh_r 2:wi_z 3:wh_z 4:wi_n 5:wh_n
    h2 w[2][6][8], wi0[3][4];
    #pragma unroll
    for (int jj = 0; jj < 2; ++jj) {
        const int j = jj ? jA1 : jA0;
        #pragma unroll
        for (int g = 0; g < 3; ++g) {
            const float* pi = &W_ih1[(j + g * HH) * HH + kq8 * 16];
            const float* ph = &W_hh1[(j + g * HH) * HH + kq8 * 16];
            #pragma unroll
            for (int m = 0; m < 8; ++m) {
                float2 f;
                f = *(const float2*)&pi[2 * m]; w[jj][2 * g][m]     = cvt2(f.x, f.y);
                f = *(const float2*)&ph[2 * m]; w[jj][2 * g + 1][m] = cvt2(f.x, f.y);
            }
        }
    }
    #pragma unroll
    for (int g = 0; g < 3; ++g) {
        const float* p0 = &W_ih0[(jx + g * HH) * IN0 + kx * 8];
        #pragma unroll
        for (int m = 0; m < 4; ++m) {
            float2 f = *(const float2*)&p0[2 * m]; wi0[g][m] = cvt2(f.x, f.y);
        }
    }
    float brz[2], bzz[2], bin[2], bhn[2];
    #pragma unroll
    for (int jj = 0; jj < 2; ++jj) {
        const int j = jj ? jA1 : jA0;
        brz[jj] = lead8 ? b_ih1[j] + b_hh1[j] : 0.f;
        bzz[jj] = lead8 ? b_ih1[j + HH] + b_hh1[j + HH] : 0.f;
        bin[jj] = lead8 ? b_ih1[j + 2 * HH] : 0.f;
        bhn[jj] = lead8 ? b_hh1[j + 2 * HH] : 0.f;
    }
    const bool leadx = (kx == 0);
    const float bg0 = leadx ? b_ih0[jx] : 0.f;
    const float bg1 = leadx ? b_ih0[jx + HH] : 0.f;
    const float bg2 = leadx ? b_ih0[jx + 2 * HH] : 0.f;

    if (tid < HH) {
        sm.hf0[0][tid] = (_Float16)0.f; sm.hf0[1][tid] = (_Float16)0.f;
        sm.hf1[0][tid] = (_Float16)0.f; sm.hf1[1][tid] = (_Float16)0.f;
    }
    if (tid < 128) {                               // stage x chunk 0
        float4 f = ((const float4*)xb)[tid];
        ((h2*)&sm.xh[0][0][0])[2 * tid]     = cvt2(f.x, f.y);
        ((h2*)&sm.xh[0][0][0])[2 * tid + 1] = cvt2(f.z, f.w);
    }
    __syncthreads();                               // barrier #1
    {   // gi0 for step 0
        H8 xc; xc.v = *(const h8*)&sm.xh[0][0][kx * 8];
        float a0 = bg0, a1 = bg1, a2 = bg2;
        #pragma unroll
        for (int q = 0; q < 4; ++q) {
            a0 = fdot2(wi0[0][q], xc.p[q], a0);
            a1 = fdot2(wi0[1][q], xc.p[q], a1);
            a2 = fdot2(wi0[2][q], xc.p[q], a2);
        }
        a0 += qxor1(a0); a0 += qxor2(a0);
        a1 += qxor1(a1); a1 += qxor2(a1);
        a2 += qxor1(a2); a2 += qxor2(a2);
        if (leadx) {
            float4 v = make_float4(a0, a1, a2, 0.f);
            *(float4*)&sm.gi0[0][jx][0] = v;
        }
    }
    __syncthreads();                               // barrier #2

    float hprev[2] = {0.f, 0.f};
    float4 pf;
    for (int s = 0; s <= TT + 4; ++s) {
        const int cur = s & 1, nxt = cur ^ 1;
        // ingest h slices early (unguarded: LDS always valid)
        H8 A0, A1, B0, B1;
        A0.v = ((const h8*)&sm.hf0[cur][kq8 * 16])[0];
        A1.v = ((const h8*)&sm.hf0[cur][kq8 * 16])[1];
        B0.v = ((const h8*)&sm.hf1[cur][kq8 * 16])[0];
        B1.v = ((const h8*)&sm.hf1[cur][kq8 * 16])[1];
        if (tid < 128 && (s & 15) == 0 && s + 16 < TT)     // issue x chunk load
            pf = ((const float4*)(xb + (size_t)(s + 16) * IN0))[tid];
        if (tid >= 256 && tid < 384 && (s & 15) == 4 && s >= 20 && (s >> 4) <= 256) {
            const int k = tid - 256;                       // flush 16 out rows
            const int fb = ((s >> 4) - 1) * 16;
            const int t = fb + (k >> 3);
            float4 v = *(const float4*)&sm.outbuf[t & 31][(k & 7) * 4];
            *(float4*)&outb[(size_t)t * NOUT + (k & 7) * 4] = v;
        }
        // h1 dots: compute unguarded (uniform), act/write guarded
        float arj[2], azj[2], anj[2], ahj[2];
        #pragma unroll
        for (int jj = 0; jj < 2; ++jj) {
            float ari = brz[jj], arh = 0.f, azi = bzz[jj], azh = 0.f;
            float ain = bin[jj], ahn = bhn[jj];
            #pragma unroll
            for (int m = 0; m < 4; ++m) {
                ari = fdot2(w[jj][0][m], A0.p[m], ari);
                arh = fdot2(w[jj][1][m], B0.p[m], arh);
                azi = fdot2(w[jj][2][m], A0.p[m], azi);
                azh = fdot2(w[jj][3][m], B0.p[m], azh);
                ain = fdot2(w[jj][4][m], A0.p[m], ain);
                ahn = fdot2(w[jj][5][m], B0.p[m], ahn);
            }
            #pragma unroll
            for (int m = 0; m < 4; ++m) {
                ari = fdot2(w[jj][0][4 + m], A1.p[m], ari);
                arh = fdot2(w[jj][1][4 + m], B1.p[m], arh);
                azi = fdot2(w[jj][2][4 + m], A1.p[m], azi);
                azh = fdot2(w[jj][3][4 + m], B1.p[m], azh);
                ain = fdot2(w[jj][4][4 + m], A1.p[m], ain);
                ahn = fdot2(w[jj][5][4 + m], B1.p[m], ahn);
            }
            float ar = ari + arh, az = azi + azh;
            ar += qxor1(ar); ar += qxor2(ar); ar = xor32sum(ar);
            az += qxor1(az); az += qxor2(az); az = xor32sum(az);
            ain += qxor1(ain); ain += qxor2(ain); ain = xor32sum(ain);
            ahn += qxor1(ahn); ahn += qxor2(ahn); ahn = xor32sum(ahn);
            arj[jj] = ar; azj[jj] = az; anj[jj] = ain; ahj[jj] = ahn;
        }
        if (s >= 1 && s <= TT) {
            #pragma unroll
            for (int jj = 0; jj < 2; ++jj) {
                const int j = jj ? jA1 : jA0;
                float rg = fast_sigmoid(arj[jj]);
                float zg = fast_sigmoid(azj[jj]);
                float ng = fast_tanh(anj[jj] + rg * ahj[jj]);
                float hn = (1.f - zg) * ng + zg * hprev[jj];
                hprev[jj] = hn;
                if (lead8) {
                    sm.hf1[nxt][j] = (_Float16)hn;
                    if (s == TT) hstack_l1[j] = hn;
                }
            }
        }
        {   // gi0 for step s+1
            const int t1 = s + 1;
            H8 xc; xc.v = *(const h8*)&sm.xh[(t1 >> 4) & 1][t1 & 15][kx * 8];
            float a0 = bg0, a1 = bg1, a2 = bg2;
            #pragma unroll
            for (int q = 0; q < 4; ++q) {
                a0 = fdot2(wi0[0][q], xc.p[q], a0);
                a1 = fdot2(wi0[1][q], xc.p[q], a1);
                a2 = fdot2(wi0[2][q], xc.p[q], a2);
            }
            a0 += qxor1(a0); a0 += qxor2(a0);
            a1 += qxor1(a1); a1 += qxor2(a1);
            a2 += qxor1(a2); a2 += qxor2(a2);
            if (leadx && s <= TT - 2) {
                float4 v = make_float4(a0, a1, a2, 0.f);
                *(float4*)&sm.gi0[nxt][jx][0] = v;
            }
        }
        if (tid < 128 && (s & 15) == 8 && s + 8 < TT) {    // commit x chunk
            const int buf = ((s >> 4) + 1) & 1;
            ((h2*)&sm.xh[buf][0][0])[2 * tid]     = cvt2(pf.x, pf.y);
            ((h2*)&sm.xh[buf][0][0])[2 * tid + 1] = cvt2(pf.z, pf.w);
        }
        __syncthreads();                                   // the ONLY per-step barrier
    }
}

// ---------------- waves 8-11: layer 0 + fused fc ----------------
__device__ __forceinline__ void role_L0(
    SM& sm, const float* __restrict__ W_hh0, const float* __restrict__ b_hh0,
    const float* __restrict__ fc_w, const float* __restrict__ fc_b,
    float* __restrict__ hstack_l0)
{
    const int u = threadIdx.x - 512;               // 0..255
    const int l6 = u & 63;
    const int kq4 = l6 & 3;                        // K-slice id (quad)
    const int jslot = ((l6 >> 2) & 15) + (u >> 6) * 16;   // 0..63
    const int jA0 = jslot, jA1 = jslot + 64;
    const bool lead = (kq4 == 0);
    const int o = u & 31, ks = u >> 5;             // fc mapping

    h2 w[2][3][16], fcr[8];
    #pragma unroll
    for (int jj = 0; jj < 2; ++jj) {
        const int j = jj ? jA1 : jA0;
        #pragma unroll
        for (int g = 0; g < 3; ++g) {
            const float* ph = &W_hh0[(size_t)(j + g * HH) * HH + kq4 * 32];
            #pragma unroll
            for (int m = 0; m < 16; ++m) {
                float2 f = *(const float2*)&ph[2 * m];
                w[jj][g][m] = cvt2(f.x, f.y);
            }
        }
    }
    #pragma unroll
    for (int m = 0; m < 8; ++m) {
        float2 f = *(const float2*)&fc_w[o * HH + ks * 16 + 2 * m];
        fcr[m] = cvt2(f.x, f.y);
    }
    float bhr[2], bhz[2], bhn[2];
    #pragma unroll
    for (int jj = 0; jj < 2; ++jj) {
        const int j = jj ? jA1 : jA0;
        bhr[jj] = lead ? b_hh0[j] : 0.f;
        bhz[jj] = lead ? b_hh0[j + HH] : 0.f;
        bhn[jj] = lead ? b_hh0[j + 2 * HH] : 0.f;
    }
    const float fcbr = (u < NOUT) ? fc_b[u] : 0.f;

    __syncthreads();                               // barrier #1 (match L1)
    __syncthreads();                               // barrier #2 (match L1)

    float hp[2] = {0.f, 0.f};
    for (int s = 0; s <= TT + 4; ++s) {
        const int cur = s & 1, nxt = cur ^ 1;
        // packed gi0 reads issued early
        float4 gia = *(const float4*)&sm.gi0[cur][jA0][0];
        float4 gib = *(const float4*)&sm.gi0[cur][jA1][0];
        H8 C0, C1, C2, C3;
        C0.v = ((const h8*)&sm.hf0[cur][kq4 * 32])[0];
        C1.v = ((const h8*)&sm.hf0[cur][kq4 * 32])[1];
        C2.v = ((const h8*)&sm.hf0[cur][kq4 * 32])[2];
        C3.v = ((const h8*)&sm.hf0[cur][kq4 * 32])[3];
        float hrj[2], hzj[2], hnj[2];
        #pragma unroll
        for (int jj = 0; jj < 2; ++jj) {
            float r0 = bhr[jj], z0 = bhz[jj], n0 = bhn[jj];
            float r1 = 0.f, z1 = 0.f, n1 = 0.f;
            #pragma unroll
            for (int m = 0; m < 4; ++m) {
                r0 = fdot2(w[jj][0][m], C0.p[m], r0);
                z0 = fdot2(w[jj][1][m], C0.p[m], z0);
                n0 = fdot2(w[jj][2][m], C0.p[m], n0);
                r1 = fdot2(w[jj][0][8 + m], C2.p[m], r1);
                z1 = fdot2(w[jj][1][8 + m], C2.p[m], z1);
                n1 = fdot2(w[jj][2][8 + m], C2.p[m], n1);
            }
            #pragma unroll
            for (int m = 0; m < 4; ++m) {
                r0 = fdot2(w[jj][0][4 + m], C1.p[m], r0);
                z0 = fdot2(w[jj][1][4 + m], C1.p[m], z0);
                n0 = fdot2(w[jj][2][4 + m], C1.p[m], n0);
                r1 = fdot2(w[jj][0][12 + m], C3.p[m], r1);
                z1 = fdot2(w[jj][1][12 + m], C3.p[m], z1);
                n1 = fdot2(w[jj][2][12 + m], C3.p[m], n1);
            }
            float rr = r0 + r1, zz = z0 + z1, nn = n0 + n1;
            rr += qxor1(rr); rr += qxor2(rr);
            zz += qxor1(zz); zz += qxor2(zz);
            nn += qxor1(nn); nn += qxor2(nn);
            hrj[jj] = rr; hzj[jj] = zz; hnj[jj] = nn;
        }
        if (s <= TT - 1) {
            #pragma unroll
            for (int jj = 0; jj < 2; ++jj) {
                const int j = jj ? jA1 : jA0;
                const float4 gi = jj ? gib : gia;
                float rg = fast_sigmoid(gi.x + hrj[jj]);
                float zg = fast_sigmoid(gi.y + hzj[jj]);
                float ng = fast_tanh(gi.z + rg * hnj[jj]);
                float hn = (1.f - zg) * ng + zg * hp[jj];
                hp[jj] = hn;
                if (lead) {
                    sm.hf0[nxt][j] = (_Float16)hn;
                    if (s == TT - 1) hstack_l0[j] = hn;
                }
            }
        }
        if (s >= 2 && s <= TT + 1) {               // fc partial on h1[s-2] (f16)
            H8 hv0, hv1;
            hv0.v = ((const h8*)&sm.hf1[cur][ks * 16])[0];
            hv1.v = ((const h8*)&sm.hf1[cur][ks * 16])[1];
            float ssum = 0.f;
            #pragma unroll
            for (int m = 0; m < 4; ++m) ssum = fdot2(fcr[m], hv0.p[m], ssum);
            #pragma unroll
            for (int m = 0; m < 4; ++m) ssum = fdot2(fcr[4 + m], hv1.p[m], ssum);
            sm.pfc[cur][o * 9 + ks] = ssum;
        }
        if (s >= 3 && s <= TT + 2 && u < NOUT) {   // fc reduce -> LDS out ring
            float ssum = fcbr;
            #pragma unroll
            for (int m = 0; m < 8; ++m) ssum += sm.pfc[nxt][u * 9 + m];
            sm.outbuf[(s - 3) & 31][u] = ssum;
        }
        __syncthreads();                           // the ONLY per-step barrier
    }
}

extern "C" __global__ void __launch_bounds__(768, 3)
gru_fused_kernel(
    const float* __restrict__ x,
    const float* __restrict__ W_ih0, const float* __restrict__ W_hh0,
    const float* __restrict__ b_ih0, const float* __restrict__ b_hh0,
    const float* __restrict__ W_ih1, const float* __restrict__ W_hh1,
    const float* __restrict__ b_ih1, const float* __restrict__ b_hh1,
    const float* __restrict__ fc_w, const float* __restrict__ fc_b,
    float* __restrict__ out, float* __restrict__ hstack)
{
    __shared__ SM sm;
    const int b = blockIdx.x;
    if (threadIdx.x < 512) {
        role_L1(sm, x + (size_t)b * TT * IN0,
                W_ih1, W_hh1, b_ih1, b_hh1, W_ih0, b_ih0,
                out + (size_t)b * TT * NOUT,
                hstack + (size_t)(BB + b) * HH);
    } else {
        role_L0(sm, W_hh0, b_hh0, fc_w, fc_b,
                hstack + (size_t)b * HH);
    }
}

extern "C" void kernel_launch(void* const* d_in, const int* in_sizes, int n_in,
                              void* d_out, int out_size, void* d_ws, size_t ws_size,
                              hipStream_t stream) {
    const float* x     = (const float*)d_in[0];
    const float* W_ih0 = (const float*)d_in[1];
    const float* W_hh0 = (const float*)d_in[2];
    const float* b_ih0 = (const float*)d_in[3];
    const float* b_hh0 = (const float*)d_in[4];
    const float* W_ih1 = (const float*)d_in[5];
    const float* W_hh1 = (const float*)d_in[6];
    const float* b_ih1 = (const float*)d_in[7];
    const float* b_hh1 = (const float*)d_in[8];
    const float* fc_w  = (const float*)d_in[9];
    const float* fc_b  = (const float*)d_in[10];

    float* out    = (float*)d_out;                 // [B,T,32]
    float* hstack = out + (size_t)BB * TT * NOUT;  // [2,B,128]

    gru_fused_kernel<<<BB, 768, 0, stream>>>(
        x, W_ih0, W_hh0, b_ih0, b_hh0,
        W_ih1, W_hh1, b_ih1, b_hh1,
        fc_w, fc_b, out, hstack);
}

// Round 7
// 5570.410 us; speedup vs baseline: 1.1628x; 1.1628x over previous
//
#include <hip/hip_runtime.h>

#define BB 64
#define TT 4096
#define IN0 32
#define HH 128
#define NOUT 32

typedef _Float16 h2 __attribute__((ext_vector_type(2)));
typedef _Float16 h8 __attribute__((ext_vector_type(8)));
union H8 { h8 v; h2 p[4]; };

// Unified single-path kernel: 512 threads, launch_bounds(512,2) -> 256-VGPR cap
// so all weights fit in TRUE VGPRs (no AGPR moves -- the r1-r5 hidden cost at
// VGPR_Count=84). Thread = (j = tid>>2, kq = tid&3): owns row j of all 3 gates
// of W_hh0 / W_ih1 / W_hh1 (K-quarter kq), gi0 kept in registers.
struct SM {
    alignas(16) _Float16 hf0[2][HH];       // h0 f16, parity by step
    alignas(16) _Float16 hf1[2][HH];       // h1 f16 (also feeds fc)
    alignas(16) _Float16 xh[2][16][IN0];   // x staged f16, 16-step chunks
    alignas(16) float    pfc[2][NOUT * 20];// fc partials, stride 20 (16B-aligned rows)
    alignas(16) float    outbuf[32][NOUT]; // out ring, flushed every 16 steps
};

__device__ __forceinline__ float fast_sigmoid(float x) {
    x = fminf(fmaxf(x, -30.f), 30.f);
    float e = __expf(-x);
    return __builtin_amdgcn_rcpf(1.f + e);
}
__device__ __forceinline__ float fast_tanh(float x) {
    x = fminf(fmaxf(x, -15.f), 15.f);
    float e = __expf(-2.f * x);
    return (1.f - e) * __builtin_amdgcn_rcpf(1.f + e);
}
__device__ __forceinline__ float fdot2(h2 a, h2 b, float c) {
#if __has_builtin(__builtin_amdgcn_fdot2)
    return __builtin_amdgcn_fdot2(a, b, c, false);   // v_dot2_f32_f16, fp32 accum
#else
    return fmaf((float)a.x, (float)b.x, fmaf((float)a.y, (float)b.y, c));
#endif
}
__device__ __forceinline__ h2 cvt2(float a, float b) {
    h2 r; r.x = (_Float16)a; r.y = (_Float16)b; return r;
}
// quad-lane butterfly via DPP (VALU pipe; r3/r4-verified)
__device__ __forceinline__ float qxor1(float v) {   // lanes 0123 -> 1032
    return __int_as_float(__builtin_amdgcn_mov_dpp(__float_as_int(v), 0xB1, 0xF, 0xF, true));
}
__device__ __forceinline__ float qxor2(float v) {   // lanes 0123 -> 2301
    return __int_as_float(__builtin_amdgcn_mov_dpp(__float_as_int(v), 0x4E, 0xF, 0xF, true));
}

extern "C" __global__ void __launch_bounds__(512, 2)
gru_unified_kernel(
    const float* __restrict__ x,
    const float* __restrict__ W_ih0, const float* __restrict__ W_hh0,
    const float* __restrict__ b_ih0, const float* __restrict__ b_hh0,
    const float* __restrict__ W_ih1, const float* __restrict__ W_hh1,
    const float* __restrict__ b_ih1, const float* __restrict__ b_hh1,
    const float* __restrict__ fc_w, const float* __restrict__ fc_b,
    float* __restrict__ out, float* __restrict__ hstack)
{
    __shared__ SM sm;
    const int b = blockIdx.x;
    const int tid = threadIdx.x;               // 0..511
    const int j = tid >> 2, kq = tid & 3;      // 128 j x 4-way K split (quad lanes)
    const bool lead = (kq == 0);
    const int o = tid & 31, ks = tid >> 5;     // fc: 32 outputs x 16-way K split
    const float* xb = x + (size_t)b * TT * IN0;
    float* outb = out + (size_t)b * TT * NOUT;
    float* hstack_l0 = hstack + (size_t)b * HH;
    float* hstack_l1 = hstack + (size_t)(BB + b) * HH;

    // ---- register-resident f16 weights (~160 VGPR) ----
    h2 wh0[3][16], wi1[3][16], wh1[3][16], wi0[3][4], wfc[4];
    #pragma unroll
    for (int g = 0; g < 3; ++g) {
        const int row = j + g * HH;
        const float* p0 = &W_hh0[(size_t)row * HH + kq * 32];
        const float* p1 = &W_ih1[(size_t)row * HH + kq * 32];
        const float* p2 = &W_hh1[(size_t)row * HH + kq * 32];
        #pragma unroll
        for (int m = 0; m < 16; ++m) {
            float2 f;
            f = *(const float2*)&p0[2 * m]; wh0[g][m] = cvt2(f.x, f.y);
            f = *(const float2*)&p1[2 * m]; wi1[g][m] = cvt2(f.x, f.y);
            f = *(const float2*)&p2[2 * m]; wh1[g][m] = cvt2(f.x, f.y);
        }
        const float* p3 = &W_ih0[(size_t)row * IN0 + kq * 8];
        #pragma unroll
        for (int m = 0; m < 4; ++m) {
            float2 f = *(const float2*)&p3[2 * m]; wi0[g][m] = cvt2(f.x, f.y);
        }
    }
    #pragma unroll
    for (int m = 0; m < 4; ++m) {
        float2 f = *(const float2*)&fc_w[(size_t)o * HH + ks * 8 + 2 * m];
        wfc[m] = cvt2(f.x, f.y);
    }
    // biases (lead lane only; reduce broadcasts the sum to all quad lanes)
    const float br1 = lead ? b_ih1[j] + b_hh1[j] : 0.f;             // L1 r (gi+gh)
    const float bz1 = lead ? b_ih1[j + HH] + b_hh1[j + HH] : 0.f;   // L1 z (gi+gh)
    const float bi1n = lead ? b_ih1[j + 2 * HH] : 0.f;
    const float bh1n = lead ? b_hh1[j + 2 * HH] : 0.f;
    const float br0 = lead ? b_hh0[j] : 0.f;
    const float bz0 = lead ? b_hh0[j + HH] : 0.f;
    const float bn0 = lead ? b_hh0[j + 2 * HH] : 0.f;
    const float bg0 = lead ? b_ih0[j] : 0.f;
    const float bg1 = lead ? b_ih0[j + HH] : 0.f;
    const float bg2 = lead ? b_ih0[j + 2 * HH] : 0.f;
    const float fcbr = fc_b[o];

    if (tid < HH) {
        sm.hf0[0][tid] = (_Float16)0.f; sm.hf0[1][tid] = (_Float16)0.f;
        sm.hf1[0][tid] = (_Float16)0.f; sm.hf1[1][tid] = (_Float16)0.f;
    }
    if (tid < 128) {                           // stage x chunk 0 (steps 0..15)
        float4 f = ((const float4*)xb)[tid];
        ((h2*)&sm.xh[0][0][0])[2 * tid]     = cvt2(f.x, f.y);
        ((h2*)&sm.xh[0][0][0])[2 * tid + 1] = cvt2(f.z, f.w);
    }
    __syncthreads();

    // gi0(x[0]) in registers
    float g0, g1, g2;
    {
        H8 xc; xc.v = *(const h8*)&sm.xh[0][0][kq * 8];
        float a0 = bg0, a1 = bg1, a2 = bg2;
        #pragma unroll
        for (int q = 0; q < 4; ++q) {
            a0 = fdot2(wi0[0][q], xc.p[q], a0);
            a1 = fdot2(wi0[1][q], xc.p[q], a1);
            a2 = fdot2(wi0[2][q], xc.p[q], a2);
        }
        a0 += qxor1(a0); a0 += qxor2(a0);
        a1 += qxor1(a1); a1 += qxor2(a1);
        a2 += qxor1(a2); a2 += qxor2(a2);
        g0 = a0; g1 = a1; g2 = a2;
    }

    // schedule (r4-verified): step s: h0[s] (s<=T-1); h1[s-1] (1<=s<=T);
    // fc partial on h1[s-2] (2<=s<=T+1); fc reduce -> ring (3<=s<=T+2);
    // ring flush every 16 steps.
    float hp0 = 0.f, hp1 = 0.f;
    float4 pf;
    for (int s = 0; s <= TT + 4; ++s) {
        const int cur = s & 1, nxt = cur ^ 1;
        if (tid < 128 && (s & 15) == 0 && s + 16 < TT)     // issue x chunk load
            pf = ((const float4*)(xb + (size_t)(s + 16) * IN0))[tid];
        if (tid >= 128 && tid < 256 && (s & 15) == 4 && s >= 20 && (s >> 4) <= 256) {
            const int k = tid - 128;                       // flush 16 out rows
            const int fb = ((s >> 4) - 1) * 16;
            const int t = fb + (k >> 3);
            float4 v = *(const float4*)&sm.outbuf[t & 31][(k & 7) * 4];
            *(float4*)&outb[(size_t)t * NOUT + (k & 7) * 4] = v;
        }
        // ---- all three recurrent matvecs, chunk-major (2 h8 live at a time) ----
        float a0r = br0, a0z = bz0, a0n = bn0;             // L0 gates
        float ar = br1, az = bz1, ain = bi1n, ahn = bh1n;  // L1 gates (r,z fused)
        #pragma unroll
        for (int c = 0; c < 4; ++c) {
            H8 A;  A.v  = ((const h8*)&sm.hf0[cur][kq * 32])[c];   // h0[s-1]
            H8 Bc; Bc.v = ((const h8*)&sm.hf1[cur][kq * 32])[c];   // h1[s-2]
            #pragma unroll
            for (int q = 0; q < 4; ++q) {
                const int m = 4 * c + q;
                a0r = fdot2(wh0[0][m], A.p[q], a0r);
                a0z = fdot2(wh0[1][m], A.p[q], a0z);
                a0n = fdot2(wh0[2][m], A.p[q], a0n);
                ar  = fdot2(wi1[0][m], A.p[q], ar);
                az  = fdot2(wi1[1][m], A.p[q], az);
                ain = fdot2(wi1[2][m], A.p[q], ain);
                ar  = fdot2(wh1[0][m], Bc.p[q], ar);
                az  = fdot2(wh1[1][m], Bc.p[q], az);
                ahn = fdot2(wh1[2][m], Bc.p[q], ahn);
            }
        }
        a0r += qxor1(a0r); a0r += qxor2(a0r);
        a0z += qxor1(a0z); a0z += qxor2(a0z);
        a0n += qxor1(a0n); a0n += qxor2(a0n);
        ar  += qxor1(ar);  ar  += qxor2(ar);
        az  += qxor1(az);  az  += qxor2(az);
        ain += qxor1(ain); ain += qxor2(ain);
        ahn += qxor1(ahn); ahn += qxor2(ahn);

        if (s <= TT - 1) {                                 // layer-0 h0[s]
            float rg = fast_sigmoid(g0 + a0r);
            float zg = fast_sigmoid(g1 + a0z);
            float ng = fast_tanh(g2 + rg * a0n);
            float hn = (1.f - zg) * ng + zg * hp0;
            hp0 = hn;
            if (lead) sm.hf0[nxt][j] = (_Float16)hn;
            if (s == TT - 1 && kq == 1) hstack_l0[j] = hn;
        }
        if (s >= 1 && s <= TT) {                           // layer-1 h1[s-1]
            float rg = fast_sigmoid(ar);
            float zg = fast_sigmoid(az);
            float ng = fast_tanh(ain + rg * ahn);
            float hn = (1.f - zg) * ng + zg * hp1;
            hp1 = hn;
            if (lead) sm.hf1[nxt][j] = (_Float16)hn;
            if (s == TT && kq == 2) hstack_l1[j] = hn;
        }
        if (s <= TT - 2) {                                 // gi0(x[s+1]) -> registers
            const int t1 = s + 1;
            H8 xc; xc.v = *(const h8*)&sm.xh[(t1 >> 4) & 1][t1 & 15][kq * 8];
            float a0 = bg0, a1 = bg1, a2 = bg2;
            #pragma unroll
            for (int q = 0; q < 4; ++q) {
                a0 = fdot2(wi0[0][q], xc.p[q], a0);
                a1 = fdot2(wi0[1][q], xc.p[q], a1);
                a2 = fdot2(wi0[2][q], xc.p[q], a2);
            }
            a0 += qxor1(a0); a0 += qxor2(a0);
            a1 += qxor1(a1); a1 += qxor2(a1);
            a2 += qxor1(a2); a2 += qxor2(a2);
            g0 = a0; g1 = a1; g2 = a2;
        }
        if (s >= 2 && s <= TT + 1) {                       // fc partial on h1[s-2] (f16)
            H8 hv; hv.v = *(const h8*)&sm.hf1[cur][ks * 8];
            float ssum = 0.f;
            #pragma unroll
            for (int m = 0; m < 4; ++m) ssum = fdot2(wfc[m], hv.p[m], ssum);
            sm.pfc[cur][o * 20 + ks] = ssum;
        }
        if (s >= 3 && s <= TT + 2 && tid < NOUT) {         // fc reduce -> out ring
            float ssum = fcbr;
            #pragma unroll
            for (int m = 0; m < 4; ++m) {
                float4 v = *(const float4*)&sm.pfc[nxt][tid * 20 + 4 * m];
                ssum += v.x + v.y + v.z + v.w;
            }
            sm.outbuf[(s - 3) & 31][tid] = ssum;
        }
        if (tid < 128 && (s & 15) == 8 && s + 8 < TT) {    // commit x chunk
            const int buf = ((s >> 4) + 1) & 1;
            ((h2*)&sm.xh[buf][0][0])[2 * tid]     = cvt2(pf.x, pf.y);
            ((h2*)&sm.xh[buf][0][0])[2 * tid + 1] = cvt2(pf.z, pf.w);
        }
        __syncthreads();                                   // the ONLY per-step barrier
    }
}

extern "C" void kernel_launch(void* const* d_in, const int* in_sizes, int n_in,
                              void* d_out, int out_size, void* d_ws, size_t ws_size,
                              hipStream_t stream) {
    const float* x     = (const float*)d_in[0];
    const float* W_ih0 = (const float*)d_in[1];
    const float* W_hh0 = (const float*)d_in[2];
    const float* b_ih0 = (const float*)d_in[3];
    const float* b_hh0 = (const float*)d_in[4];
    const float* W_ih1 = (const float*)d_in[5];
    const float* W_hh1 = (const float*)d_in[6];
    const float* b_ih1 = (const float*)d_in[7];
    const float* b_hh1 = (const float*)d_in[8];
    const float* fc_w  = (const float*)d_in[9];
    const float* fc_b  = (const float*)d_in[10];

    float* out    = (float*)d_out;                 // [B,T,32]
    float* hstack = out + (size_t)BB * TT * NOUT;  // [2,B,128]

    gru_unified_kernel<<<BB, 512, 0, stream>>>(
        x, W_ih0, W_hh0, b_ih0, b_hh0,
        W_ih1, W_hh1, b_ih1, b_hh1,
        fc_w, fc_b, out, hstack);
}

// Round 8
// 4330.111 us; speedup vs baseline: 1.4958x; 1.2864x over previous
//
#include <hip/hip_runtime.h>

#define BB 64
#define TT 4096
#define IN0 32
#define HH 128
#define NOUT 32

typedef _Float16 h2 __attribute__((ext_vector_type(2)));
typedef _Float16 h8v __attribute__((ext_vector_type(8)));
typedef float f32x4 __attribute__((ext_vector_type(4)));
union H8 { h8v v; h2 p[4]; };

// MFMA formulation: 512 threads / 8 waves per WG, one WG per batch element.
// Wave w owns output rows j = 16w..16w+15 of BOTH layers. Each step:
// 39 mfma_f32_16x16x32_f16 per wave (M=1 usage: only D row 0 consumed).
// Weights live in per-wave B-fragments (loaded once; AGPR-resident is free
// for MFMA -- dodges the r1-r7 register-demotion wall). No DPP reduces.
struct SM {
    alignas(16) _Float16 hf0[2][HH];        // h0 f16, parity by step
    alignas(16) _Float16 hf1[2][HH];        // h1 f16 (also feeds fc)
    alignas(16) _Float16 xh[2][16][IN0];    // x staged f16, 16-step chunks
    alignas(16) float    pfc[2][NOUT * 20]; // fc partials (16-way K-split)
    alignas(16) float    outbuf[32][NOUT];  // out ring, flushed every 16 steps
};

__device__ __forceinline__ float fast_sigmoid(float x) {
    x = fminf(fmaxf(x, -30.f), 30.f);
    float e = __expf(-x);
    return __builtin_amdgcn_rcpf(1.f + e);
}
__device__ __forceinline__ float fast_tanh(float x) {
    x = fminf(fmaxf(x, -15.f), 15.f);
    float e = __expf(-2.f * x);
    return (1.f - e) * __builtin_amdgcn_rcpf(1.f + e);
}
__device__ __forceinline__ float fdot2(h2 a, h2 b, float c) {
#if __has_builtin(__builtin_amdgcn_fdot2)
    return __builtin_amdgcn_fdot2(a, b, c, false);
#else
    return fmaf((float)a.x, (float)b.x, fmaf((float)a.y, (float)b.y, c));
#endif
}
__device__ __forceinline__ h2 cvt2(float a, float b) {
    h2 r; r.x = (_Float16)a; r.y = (_Float16)b; return r;
}
__device__ __forceinline__ f32x4 MF(h8v a, h8v b, f32x4 c) {
    return __builtin_amdgcn_mfma_f32_16x16x32_f16(a, b, c, 0, 0, 0);
}

extern "C" __global__ __launch_bounds__(512)
__attribute__((amdgpu_waves_per_eu(2, 2)))
void gru_mfma_kernel(
    const float* __restrict__ x,
    const float* __restrict__ W_ih0, const float* __restrict__ W_hh0,
    const float* __restrict__ b_ih0, const float* __restrict__ b_hh0,
    const float* __restrict__ W_ih1, const float* __restrict__ W_hh1,
    const float* __restrict__ b_ih1, const float* __restrict__ b_hh1,
    const float* __restrict__ fc_w, const float* __restrict__ fc_b,
    float* __restrict__ out, float* __restrict__ hstack)
{
    __shared__ SM sm;
    const int b = blockIdx.x;
    const int tid = threadIdx.x;          // 0..511
    const int w = tid >> 6;               // wave 0..7
    const int l = tid & 63;               // lane
    const int ln = l & 15;                // D col / A row / B col index
    const int kg = (l >> 4) * 8;          // lane's k-offset within a 32-chunk
    const int jw = 16 * w + ln;           // output row this lane handles (lanes 0-15)
    const int o = tid & 31, ks = tid >> 5;// fc mapping: 32 outputs x 16 K-slices
    const float* xb = x + (size_t)b * TT * IN0;
    float* outb = out + (size_t)b * TT * NOUT;
    float* hstack_l0 = hstack + (size_t)b * HH;
    float* hstack_l1 = hstack + (size_t)(BB + b) * HH;

    // ---- B-fragments: this wave's weight slice, f32 -> f16, loaded once ----
    // B layout (symmetric to A): lane holds col ln, k = kb + kg + 0..7.
    // Any k-permutation assumption cancels between A and B fragments.
    auto LDB = [&](const float* W, int ldk, int row, int kb) -> h8v {
        const float* p = W + (size_t)row * ldk + kb + kg;
        float4 f0 = *(const float4*)p;
        float4 f1 = *(const float4*)(p + 4);
        H8 u;
        u.p[0] = cvt2(f0.x, f0.y); u.p[1] = cvt2(f0.z, f0.w);
        u.p[2] = cvt2(f1.x, f1.y); u.p[3] = cvt2(f1.z, f1.w);
        return u.v;
    };
    h8v Br1i[4], Br1h[4], Bz1i[4], Bz1h[4], Bn1i[4], Bn1h[4];
    h8v Br0[4], Bz0[4], Bh0[4];
    #pragma unroll
    for (int c = 0; c < 4; ++c) {
        Br1i[c] = LDB(W_ih1, HH, jw,       32 * c);
        Bz1i[c] = LDB(W_ih1, HH, jw + 128, 32 * c);
        Bn1i[c] = LDB(W_ih1, HH, jw + 256, 32 * c);
        Br1h[c] = LDB(W_hh1, HH, jw,       32 * c);
        Bz1h[c] = LDB(W_hh1, HH, jw + 128, 32 * c);
        Bn1h[c] = LDB(W_hh1, HH, jw + 256, 32 * c);
        Br0[c]  = LDB(W_hh0, HH, jw,       32 * c);
        Bz0[c]  = LDB(W_hh0, HH, jw + 128, 32 * c);
        Bh0[c]  = LDB(W_hh0, HH, jw + 256, 32 * c);
    }
    const h8v Br0x = LDB(W_ih0, IN0, jw,       0);
    const h8v Bz0x = LDB(W_ih0, IN0, jw + 128, 0);
    const h8v Bn0x = LDB(W_ih0, IN0, jw + 256, 0);

    // biases (post-added at extraction; r/z get gi+gh biases fused)
    const float bvr1 = b_ih1[jw] + b_hh1[jw];
    const float bvz1 = b_ih1[jw + 128] + b_hh1[jw + 128];
    const float bvi1 = b_ih1[jw + 256];
    const float bvh1 = b_hh1[jw + 256];
    const float bvr0 = b_ih0[jw] + b_hh0[jw];
    const float bvz0 = b_ih0[jw + 128] + b_hh0[jw + 128];
    const float bvi0 = b_ih0[jw + 256];
    const float bvh0 = b_hh0[jw + 256];
    // fc weights for the dot2 side path
    h2 wfc[4];
    #pragma unroll
    for (int m = 0; m < 4; ++m) {
        float2 f = *(const float2*)&fc_w[(size_t)o * HH + ks * 8 + 2 * m];
        wfc[m] = cvt2(f.x, f.y);
    }
    const float fcbr = fc_b[o];
    const f32x4 z4 = {0.f, 0.f, 0.f, 0.f};

    if (tid < HH) {
        sm.hf0[0][tid] = (_Float16)0.f; sm.hf0[1][tid] = (_Float16)0.f;
        sm.hf1[0][tid] = (_Float16)0.f; sm.hf1[1][tid] = (_Float16)0.f;
    }
    if (tid < 128) {                        // stage x chunk 0 (steps 0..15)
        float4 f = ((const float4*)xb)[tid];
        ((h2*)&sm.xh[0][0][0])[2 * tid]     = cvt2(f.x, f.y);
        ((h2*)&sm.xh[0][0][0])[2 * tid + 1] = cvt2(f.z, f.w);
    }
    __syncthreads();

    // schedule (r4/r7-verified): step s: h0[s] (s<=T-1); h1[s-1] (1<=s<=T);
    // fc partial on h1[s-2]; fc reduce -> ring; ring flush every 16 steps.
    float hp0 = 0.f, hp1 = 0.f;
    float4 pf;
    for (int s = 0; s <= TT + 4; ++s) {
        const int cur = s & 1, nxt = cur ^ 1;
        if (tid < 128 && (s & 15) == 0 && s + 16 < TT)     // issue x chunk load
            pf = ((const float4*)(xb + (size_t)(s + 16) * IN0))[tid];
        if (tid >= 128 && tid < 256 && (s & 15) == 4 && s >= 20 && (s >> 4) <= 256) {
            const int k = tid - 128;                       // flush 16 out rows
            const int fb = ((s >> 4) - 1) * 16;
            const int t = fb + (k >> 3);
            float4 v = *(const float4*)&sm.outbuf[t & 31][(k & 7) * 4];
            *(float4*)&outb[(size_t)t * NOUT + (k & 7) * 4] = v;
        }
        // ---- A-fragments from LDS (1 ds_read_b128 each; rows 1-15 garbage,
        //      which only pollutes unused D rows) + 39 MFMA ----
        const _Float16* h0b = &sm.hf0[cur][0] + kg;
        const _Float16* h1b = &sm.hf1[cur][0] + kg;
        const _Float16* xr  = &sm.xh[(s >> 4) & 1][s & 15][0] + kg;
        h8v a0 = *(const h8v*)(h0b);
        h8v a1 = *(const h8v*)(h1b);
        f32x4 r1  = MF(a0, Br1i[0], z4); r1 = MF(a1, Br1h[0], r1);
        f32x4 zz1 = MF(a0, Bz1i[0], z4); zz1 = MF(a1, Bz1h[0], zz1);
        f32x4 n1i = MF(a0, Bn1i[0], z4);
        f32x4 n1h = MF(a1, Bn1h[0], z4);
        f32x4 r0  = MF(a0, Br0[0], z4);
        f32x4 zz0 = MF(a0, Bz0[0], z4);
        f32x4 n0h = MF(a0, Bh0[0], z4);
        #pragma unroll
        for (int c = 1; c < 4; ++c) {
            a0 = *(const h8v*)(h0b + 32 * c);
            a1 = *(const h8v*)(h1b + 32 * c);
            r1  = MF(a0, Br1i[c], r1);  r1  = MF(a1, Br1h[c], r1);
            zz1 = MF(a0, Bz1i[c], zz1); zz1 = MF(a1, Bz1h[c], zz1);
            n1i = MF(a0, Bn1i[c], n1i);
            n1h = MF(a1, Bn1h[c], n1h);
            r0  = MF(a0, Br0[c], r0);
            zz0 = MF(a0, Bz0[c], zz0);
            n0h = MF(a0, Bh0[c], n0h);
        }
        h8v ax = *(const h8v*)xr;
        r0  = MF(ax, Br0x, r0);
        zz0 = MF(ax, Bz0x, zz0);
        f32x4 n0i = MF(ax, Bn0x, z4);

        // ---- activations (D row 0 = lanes 0-15, reg .x; m89-verified) ----
        {   // layer-0 h0[s]
            float rg = fast_sigmoid(r0.x + bvr0);
            float zg = fast_sigmoid(zz0.x + bvz0);
            float ng = fast_tanh(n0i.x + bvi0 + rg * (n0h.x + bvh0));
            float hn = (1.f - zg) * ng + zg * hp0;
            if (s <= TT - 1) {
                hp0 = hn;
                if (l < 16) {
                    sm.hf0[nxt][jw] = (_Float16)hn;
                    if (s == TT - 1) hstack_l0[jw] = hn;
                }
            }
        }
        {   // layer-1 h1[s-1]
            float rg = fast_sigmoid(r1.x + bvr1);
            float zg = fast_sigmoid(zz1.x + bvz1);
            float ng = fast_tanh(n1i.x + bvi1 + rg * (n1h.x + bvh1));
            float hn = (1.f - zg) * ng + zg * hp1;
            if (s >= 1 && s <= TT) {
                hp1 = hn;
                if (l < 16) {
                    sm.hf1[nxt][jw] = (_Float16)hn;
                    if (s == TT) hstack_l1[jw] = hn;
                }
            }
        }
        // ---- fused fc on h1[s-2] (dot2 side path, VALU pipe) ----
        if (s >= 2 && s <= TT + 1) {
            H8 hv; hv.v = *(const h8v*)&sm.hf1[cur][ks * 8];
            float ssum = 0.f;
            #pragma unroll
            for (int m = 0; m < 4; ++m) ssum = fdot2(wfc[m], hv.p[m], ssum);
            sm.pfc[cur][o * 20 + ks] = ssum;
        }
        if (s >= 3 && s <= TT + 2 && tid < NOUT) {
            float ssum = fcbr;
            #pragma unroll
            for (int m = 0; m < 4; ++m) {
                float4 v = *(const float4*)&sm.pfc[nxt][tid * 20 + 4 * m];
                ssum += v.x + v.y + v.z + v.w;
            }
            sm.outbuf[(s - 3) & 31][tid] = ssum;
        }
        if (tid < 128 && (s & 15) == 8 && s + 8 < TT) {    // commit x chunk
            const int buf = ((s >> 4) + 1) & 1;
            ((h2*)&sm.xh[buf][0][0])[2 * tid]     = cvt2(pf.x, pf.y);
            ((h2*)&sm.xh[buf][0][0])[2 * tid + 1] = cvt2(pf.z, pf.w);
        }
        __syncthreads();                                   // the ONLY per-step barrier
    }
}

extern "C" void kernel_launch(void* const* d_in, const int* in_sizes, int n_in,
                              void* d_out, int out_size, void* d_ws, size_t ws_size,
                              hipStream_t stream) {
    const float* x     = (const float*)d_in[0];
    const float* W_ih0 = (const float*)d_in[1];
    const float* W_hh0 = (const float*)d_in[2];
    const float* b_ih0 = (const float*)d_in[3];
    const float* b_hh0 = (const float*)d_in[4];
    const float* W_ih1 = (const float*)d_in[5];
    const float* W_hh1 = (const float*)d_in[6];
    const float* b_ih1 = (const float*)d_in[7];
    const float* b_hh1 = (const float*)d_in[8];
    const float* fc_w  = (const float*)d_in[9];
    const float* fc_b  = (const float*)d_in[10];

    float* out    = (float*)d_out;                 // [B,T,32]
    float* hstack = out + (size_t)BB * TT * NOUT;  // [2,B,128]

    gru_mfma_kernel<<<BB, 512, 0, stream>>>(
        x, W_ih0, W_hh0, b_ih0, b_hh0,
        W_ih1, W_hh1, b_ih1, b_hh1,
        fc_w, fc_b, out, hstack);
}

// Round 9
// 4045.288 us; speedup vs baseline: 1.6011x; 1.0704x over previous
//
#include <hip/hip_runtime.h>

#define BB 64
#define TT 4096
#define IN0 32
#define HH 128
#define NOUT 32

typedef _Float16 h2 __attribute__((ext_vector_type(2)));
typedef _Float16 h8v __attribute__((ext_vector_type(8)));
typedef float f32x4 __attribute__((ext_vector_type(4)));
union H8 { h8v v; h2 p[4]; };

// MFMA formulation (r8-verified) + r9: 2x step-unroll with literal parity,
// fc folded into one spare MFMA per wave, statically-indexed A-frag arrays.
// 512 threads / 8 waves per WG, one WG per batch element.
struct SM {
    alignas(16) _Float16 hf0[2][HH];        // h0 f16, parity by step
    alignas(16) _Float16 hf1[2][HH];        // h1 f16 (also feeds fc)
    alignas(16) _Float16 xh[2][16][IN0];    // x staged f16, 16-step chunks
    alignas(16) float    pfc[2][NOUT * 20]; // fc partials (4 k-chunks used)
    alignas(16) float    outbuf[32][NOUT];  // out ring, flushed every 16 steps
};

__device__ __forceinline__ float fast_sigmoid(float x) {
    x = fminf(fmaxf(x, -30.f), 30.f);
    float e = __expf(-x);
    return __builtin_amdgcn_rcpf(1.f + e);
}
__device__ __forceinline__ float fast_tanh(float x) {
    x = fminf(fmaxf(x, -15.f), 15.f);
    float e = __expf(-2.f * x);
    return (1.f - e) * __builtin_amdgcn_rcpf(1.f + e);
}
__device__ __forceinline__ h2 cvt2(float a, float b) {
    h2 r; r.x = (_Float16)a; r.y = (_Float16)b; return r;
}
__device__ __forceinline__ f32x4 MF(h8v a, h8v b, f32x4 c) {
    return __builtin_amdgcn_mfma_f32_16x16x32_f16(a, b, c, 0, 0, 0);
}

extern "C" __global__ __launch_bounds__(512)
__attribute__((amdgpu_waves_per_eu(2, 2)))
void gru_mfma_kernel(
    const float* __restrict__ x,
    const float* __restrict__ W_ih0, const float* __restrict__ W_hh0,
    const float* __restrict__ b_ih0, const float* __restrict__ b_hh0,
    const float* __restrict__ W_ih1, const float* __restrict__ W_hh1,
    const float* __restrict__ b_ih1, const float* __restrict__ b_hh1,
    const float* __restrict__ fc_w, const float* __restrict__ fc_b,
    float* __restrict__ out, float* __restrict__ hstack)
{
    __shared__ SM sm;
    const int b = blockIdx.x;
    const int tid = threadIdx.x;          // 0..511
    const int w = tid >> 6;               // wave 0..7
    const int l = tid & 63;               // lane
    const int ln = l & 15;                // D col / A row / B col index
    const int kg = (l >> 4) * 8;          // lane's k-offset within a 32-chunk
    const int jw = 16 * w + ln;           // output row this lane handles
    const int ofc = 16 * (w & 1) + ln;    // fc out-row this lane's MFMA covers
    const int cfc = w >> 1;               // fc k-chunk this wave covers
    const int fco = kg + 32 * cfc;        // fc A-frag LDS offset (halves)
    const float* xb = x + (size_t)b * TT * IN0;
    float* outb = out + (size_t)b * TT * NOUT;
    float* hstack_l0 = hstack + (size_t)b * HH;
    float* hstack_l1 = hstack + (size_t)(BB + b) * HH;

    // ---- B-fragments: this wave's weight slice, f32 -> f16, loaded once ----
    auto LDB = [&](const float* W, int ldk, int row, int kb) -> h8v {
        const float* p = W + (size_t)row * ldk + kb + kg;
        float4 f0 = *(const float4*)p;
        float4 f1 = *(const float4*)(p + 4);
        H8 u;
        u.p[0] = cvt2(f0.x, f0.y); u.p[1] = cvt2(f0.z, f0.w);
        u.p[2] = cvt2(f1.x, f1.y); u.p[3] = cvt2(f1.z, f1.w);
        return u.v;
    };
    h8v Br1i[4], Br1h[4], Bz1i[4], Bz1h[4], Bn1i[4], Bn1h[4];
    h8v Br0[4], Bz0[4], Bh0[4];
    #pragma unroll
    for (int c = 0; c < 4; ++c) {
        Br1i[c] = LDB(W_ih1, HH, jw,       32 * c);
        Bz1i[c] = LDB(W_ih1, HH, jw + 128, 32 * c);
        Bn1i[c] = LDB(W_ih1, HH, jw + 256, 32 * c);
        Br1h[c] = LDB(W_hh1, HH, jw,       32 * c);
        Bz1h[c] = LDB(W_hh1, HH, jw + 128, 32 * c);
        Bn1h[c] = LDB(W_hh1, HH, jw + 256, 32 * c);
        Br0[c]  = LDB(W_hh0, HH, jw,       32 * c);
        Bz0[c]  = LDB(W_hh0, HH, jw + 128, 32 * c);
        Bh0[c]  = LDB(W_hh0, HH, jw + 256, 32 * c);
    }
    const h8v Br0x = LDB(W_ih0, IN0, jw,       0);
    const h8v Bz0x = LDB(W_ih0, IN0, jw + 128, 0);
    const h8v Bn0x = LDB(W_ih0, IN0, jw + 256, 0);
    const h8v Bfc  = LDB(fc_w,  HH,  ofc,      32 * cfc);

    // biases (post-added at extraction; r/z get gi+gh biases fused)
    const float bvr1 = b_ih1[jw] + b_hh1[jw];
    const float bvz1 = b_ih1[jw + 128] + b_hh1[jw + 128];
    const float bvi1 = b_ih1[jw + 256];
    const float bvh1 = b_hh1[jw + 256];
    const float bvr0 = b_ih0[jw] + b_hh0[jw];
    const float bvz0 = b_ih0[jw + 128] + b_hh0[jw + 128];
    const float bvi0 = b_ih0[jw + 256];
    const float bvh0 = b_hh0[jw + 256];
    const float fcbr = (tid < NOUT) ? fc_b[tid] : 0.f;
    const f32x4 z4 = {0.f, 0.f, 0.f, 0.f};

    if (tid < HH) {
        sm.hf0[0][tid] = (_Float16)0.f; sm.hf0[1][tid] = (_Float16)0.f;
        sm.hf1[0][tid] = (_Float16)0.f; sm.hf1[1][tid] = (_Float16)0.f;
    }
    if (tid < 128) {                        // stage x chunk 0 (steps 0..15)
        float4 f = ((const float4*)xb)[tid];
        ((h2*)&sm.xh[0][0][0])[2 * tid]     = cvt2(f.x, f.y);
        ((h2*)&sm.xh[0][0][0])[2 * tid + 1] = cvt2(f.z, f.w);
    }
    __syncthreads();

    // schedule (r4/r8-verified): step s: h0[s] (s<=T-1); h1[s-1] (1<=s<=T);
    // fc partial on h1[s-2]; fc reduce -> ring (out[s-3]); flush every 16 steps.
    float hp0 = 0.f, hp1 = 0.f;
    float4 pf;

    auto body = [&](int s, int cur) {       // cur is a LITERAL 0/1 at call sites
        const int nxt = cur ^ 1;
        if (tid < 128 && (s & 15) == 0 && s + 16 < TT)     // issue x chunk load
            pf = ((const float4*)(xb + (size_t)(s + 16) * IN0))[tid];
        if (tid >= 128 && tid < 256 && (s & 15) == 4 && s >= 20 && (s >> 4) <= 256) {
            const int k = tid - 128;                       // flush 16 out rows
            const int fb = ((s >> 4) - 1) * 16;
            const int t = fb + (k >> 3);
            float4 v = *(const float4*)&sm.outbuf[t & 31][(k & 7) * 4];
            *(float4*)&outb[(size_t)t * NOUT + (k & 7) * 4] = v;
        }
        // ---- A-fragments (static-index arrays; all rows carry the same h) ----
        const _Float16* h0b = &sm.hf0[cur][0] + kg;        // cur literal: static base
        const _Float16* h1b = &sm.hf1[cur][0] + kg;
        h8v a0[4], a1[4];
        #pragma unroll
        for (int c = 0; c < 4; ++c) {
            a0[c] = *(const h8v*)(h0b + 32 * c);
            a1[c] = *(const h8v*)(h1b + 32 * c);
        }
        h8v ax  = *(const h8v*)(&sm.xh[(s >> 4) & 1][s & 15][0] + kg);
        h8v afc = *(const h8v*)(&sm.hf1[cur][0] + fco);     // fc A-frag (own chunk)
        // ---- 40 MFMA ----
        f32x4 r1  = MF(a0[0], Br1i[0], z4); r1  = MF(a1[0], Br1h[0], r1);
        f32x4 zz1 = MF(a0[0], Bz1i[0], z4); zz1 = MF(a1[0], Bz1h[0], zz1);
        f32x4 n1i = MF(a0[0], Bn1i[0], z4);
        f32x4 n1h = MF(a1[0], Bn1h[0], z4);
        f32x4 r0  = MF(a0[0], Br0[0], z4);
        f32x4 zz0 = MF(a0[0], Bz0[0], z4);
        f32x4 n0h = MF(a0[0], Bh0[0], z4);
        f32x4 pacc = MF(afc, Bfc, z4);                      // fc partial (this chunk)
        #pragma unroll
        for (int c = 1; c < 4; ++c) {
            r1  = MF(a0[c], Br1i[c], r1);  r1  = MF(a1[c], Br1h[c], r1);
            zz1 = MF(a0[c], Bz1i[c], zz1); zz1 = MF(a1[c], Bz1h[c], zz1);
            n1i = MF(a0[c], Bn1i[c], n1i);
            n1h = MF(a1[c], Bn1h[c], n1h);
            r0  = MF(a0[c], Br0[c], r0);
            zz0 = MF(a0[c], Bz0[c], zz0);
            n0h = MF(a0[c], Bh0[c], n0h);
        }
        r0  = MF(ax, Br0x, r0);
        zz0 = MF(ax, Bz0x, zz0);
        f32x4 n0i = MF(ax, Bn0x, z4);

        // ---- activations (row-duplicated D: .x valid in all lanes) ----
        {   // layer-0 h0[s]
            float rg = fast_sigmoid(r0.x + bvr0);
            float zg = fast_sigmoid(zz0.x + bvz0);
            float ng = fast_tanh(n0i.x + bvi0 + rg * (n0h.x + bvh0));
            float hn = (1.f - zg) * ng + zg * hp0;
            if (s <= TT - 1) {
                hp0 = hn;
                if (l < 16) {
                    sm.hf0[nxt][jw] = (_Float16)hn;
                    if (s == TT - 1) hstack_l0[jw] = hn;
                }
            }
        }
        {   // layer-1 h1[s-1]
            float rg = fast_sigmoid(r1.x + bvr1);
            float zg = fast_sigmoid(zz1.x + bvz1);
            float ng = fast_tanh(n1i.x + bvi1 + rg * (n1h.x + bvh1));
            float hn = (1.f - zg) * ng + zg * hp1;
            if (s >= 1 && s <= TT) {
                hp1 = hn;
                if (l < 16) {
                    sm.hf1[nxt][jw] = (_Float16)hn;
                    if (s == TT) hstack_l1[jw] = hn;
                }
            }
        }
        // ---- fc partial store + reduce ----
        if (s >= 2 && s <= TT + 1 && l < 16)
            sm.pfc[cur][ofc * 20 + cfc] = pacc.x;
        if (s >= 3 && s <= TT + 2 && tid < NOUT) {
            float ssum = fcbr;
            ssum += sm.pfc[nxt][tid * 20 + 0];
            ssum += sm.pfc[nxt][tid * 20 + 1];
            ssum += sm.pfc[nxt][tid * 20 + 2];
            ssum += sm.pfc[nxt][tid * 20 + 3];
            sm.outbuf[(s - 3) & 31][tid] = ssum;
        }
        if (tid < 128 && (s & 15) == 8 && s + 8 < TT) {    // commit x chunk
            const int buf = ((s >> 4) + 1) & 1;
            ((h2*)&sm.xh[buf][0][0])[2 * tid]     = cvt2(pf.x, pf.y);
            ((h2*)&sm.xh[buf][0][0])[2 * tid + 1] = cvt2(pf.z, pf.w);
        }
        __syncthreads();                                   // the ONLY per-step barrier
    };

    for (int s2 = 0; s2 <= TT + 4; s2 += 2) {
        body(s2, 0);        // literal parity: static LDS addressing per copy
        body(s2 + 1, 1);    // (s=TT+5 tail iteration is guard-dead and harmless)
    }
}

extern "C" void kernel_launch(void* const* d_in, const int* in_sizes, int n_in,
                              void* d_out, int out_size, void* d_ws, size_t ws_size,
                              hipStream_t stream) {
    const float* x     = (const float*)d_in[0];
    const float* W_ih0 = (const float*)d_in[1];
    const float* W_hh0 = (const float*)d_in[2];
    const float* b_ih0 = (const float*)d_in[3];
    const float* b_hh0 = (const float*)d_in[4];
    const float* W_ih1 = (const float*)d_in[5];
    const float* W_hh1 = (const float*)d_in[6];
    const float* b_ih1 = (const float*)d_in[7];
    const float* b_hh1 = (const float*)d_in[8];
    const float* fc_w  = (const float*)d_in[9];
    const float* fc_b  = (const float*)d_in[10];

    float* out    = (float*)d_out;                 // [B,T,32]
    float* hstack = out + (size_t)BB * TT * NOUT;  // [2,B,128]

    gru_mfma_kernel<<<BB, 512, 0, stream>>>(
        x, W_ih0, W_hh0, b_ih0, b_hh0,
        W_ih1, W_hh1, b_ih1, b_hh1,
        fc_w, fc_b, out, hstack);
}